// Round 7
// baseline (206.704 us; speedup 1.0000x reference)
//
#include <hip/hip_runtime.h>

typedef int v4i  __attribute__((ext_vector_type(4)));
typedef int v16i __attribute__((ext_vector_type(16)));

constexpr int Kdim = 4096;
constexpr int Ndim = 4096;
constexpr int MtotC = 8192;
constexpr int BM = 256;
constexpr int BN = 256;
constexpr int BKB = 128;          // K-bytes per LDS tile (2 halves of 64B)
constexpr int NT = Kdim / BKB;    // 32 K-tiles

// ---------------- pack int32 -> int8 (both tensors, one launch) ----------------
__global__ void pack_i32_to_i8(const int* __restrict__ xq, const int* __restrict__ wq,
                               signed char* __restrict__ x8, signed char* __restrict__ w8,
                               size_t nx4, size_t nw4) {
    size_t i = (size_t)blockIdx.x * blockDim.x + threadIdx.x;
    size_t stride = (size_t)gridDim.x * blockDim.x;
    size_t tot = nx4 + nw4;
    for (size_t j = i; j < tot; j += stride) {
        if (j < nx4) {
            const int4 v = ((const int4*)xq)[j];
            char4 c;
            c.x = (signed char)v.x; c.y = (signed char)v.y;
            c.z = (signed char)v.z; c.w = (signed char)v.w;
            ((char4*)x8)[j] = c;
        } else {
            const size_t k = j - nx4;
            const int4 v = ((const int4*)wq)[k];
            char4 c;
            c.x = (signed char)v.x; c.y = (signed char)v.y;
            c.z = (signed char)v.z; c.w = (signed char)v.w;
            ((char4*)w8)[k] = c;
        }
    }
}

// ---------------- int8 GEMM, 256x256 tile, 32x32x32 MFMA, 1-barrier phases ----------------
// LDS: 2 bufs x 2 halves x (A 16KB + B 16KB) = 128KB.
// Half h of K-tile t holds K-bytes [t*128 + h*64, +64) for 256 A-rows + 256 B-rows.
// 16B-slot swizzle within a 64B row: slot' = slot ^ ((row>>1)&3).
__global__ __launch_bounds__(512, 2) void i8gemm_kernel(
    const signed char* __restrict__ A,
    const signed char* __restrict__ W,
    const float* __restrict__ sx,
    const float* __restrict__ wsc,
    const float* __restrict__ bias,
    float* __restrict__ C)
{
    extern __shared__ signed char smem[];

    const int tid  = threadIdx.x;
    const int wave = tid >> 6;
    const int lane = tid & 63;
    const int wr = wave >> 2;     // 0..1  (128-row strip)
    const int wc = wave & 3;      // 0..3  (64-col strip)

    // XCD-aware swizzle: 8 regions of 8bm x 8bn
    const int xr_ = blockIdx.x & 7;
    const int idx = blockIdx.x >> 3;
    const int bm = ((xr_ & 3) * 8 + (idx & 7)) * BM;
    const int bn = ((xr_ >> 2) * 8 + (idx >> 3)) * BN;

    // ---- staging constants (per thread: 1 A + 1 B gload_lds per STG) ----
    const int srow_in = wave * 16 + (lane >> 2);            // 0..127
    const int sslotp  = lane & 3;                           // LDS slot'
    const int gslot   = sslotp ^ ((srow_in >> 1) & 3);      // pre-inverse-swizzled global slot
    const signed char* Ag = A + (size_t)(bm + srow_in) * Kdim + gslot * 16;
    const signed char* Wg = W + (size_t)(bn + srow_in) * Kdim + gslot * 16;
    const int sdst = srow_in * 64 + sslotp * 16;            // within-half LDS offset

    // ---- fragment read constants (32x32x32 layout: row/col = lane&31, k-16B-half = lane>>5) ----
    const int l31 = lane & 31;
    const int hi  = lane >> 5;
    const int xm  = (l31 >> 1) & 3;                         // read-side swizzle mask
    const int ps0 = ((hi)     ^ xm) * 16;                   // k-slice 0 within 64B half
    const int ps1 = ((2 + hi) ^ xm) * 16;                   // k-slice 1
    const int aro = (wr * 128 + l31) * 64;                  // + rb*2048 + half*32768 + ps
    const int bro = 16384 + (wc * 64 + l31) * 64;           // + cb*2048 + half*32768 + ps

    v16i acc[4][2];
#pragma unroll
    for (int f = 0; f < 4; ++f)
#pragma unroll
        for (int g = 0; g < 2; ++g)
#pragma unroll
            for (int e = 0; e < 16; ++e) acc[f][g][e] = 0;

#define STG(KT, HALF, RB) do {                                                         \
    __builtin_amdgcn_global_load_lds(                                                  \
        (const __attribute__((address_space(1))) void*)(Ag + (size_t)(RB) * Kdim + (KT) * BKB + (HALF) * 64), \
        (__attribute__((address_space(3))) void*)(smem + ((KT) & 1) * 65536 + (HALF) * 32768 + (RB) * 64 + sdst), \
        16, 0, 0);                                                                     \
    __builtin_amdgcn_global_load_lds(                                                  \
        (const __attribute__((address_space(1))) void*)(Wg + (size_t)(RB) * Kdim + (KT) * BKB + (HALF) * 64), \
        (__attribute__((address_space(3))) void*)(smem + ((KT) & 1) * 65536 + (HALF) * 32768 + 16384 + (RB) * 64 + sdst), \
        16, 0, 0);                                                                     \
} while (0)

#define BAR   __builtin_amdgcn_s_barrier()
#define LGKM0 asm volatile("s_waitcnt lgkmcnt(0)" ::: "memory")
#define PRIO1 __builtin_amdgcn_s_setprio(1)
#define PRIO0 __builtin_amdgcn_s_setprio(0)

// reads: rb pair {0,1} + all bv for one half
#define PH_READ_AB(HALF) do {                                                          \
    bv[0] = *(const v4i*)(bufb + (HALF) * 32768 + bro +    0 + ps0);                   \
    bv[1] = *(const v4i*)(bufb + (HALF) * 32768 + bro + 2048 + ps0);                   \
    bv[2] = *(const v4i*)(bufb + (HALF) * 32768 + bro +    0 + ps1);                   \
    bv[3] = *(const v4i*)(bufb + (HALF) * 32768 + bro + 2048 + ps1);                   \
    av[0] = *(const v4i*)(bufb + (HALF) * 32768 + aro +    0 + ps0);                   \
    av[1] = *(const v4i*)(bufb + (HALF) * 32768 + aro + 2048 + ps0);                   \
    av[2] = *(const v4i*)(bufb + (HALF) * 32768 + aro +    0 + ps1);                   \
    av[3] = *(const v4i*)(bufb + (HALF) * 32768 + aro + 2048 + ps1);                   \
} while (0)

// reads: rb pair {2,3} for one half (bv reused from PH_READ_AB)
#define PH_READ_A2(HALF) do {                                                          \
    av[0] = *(const v4i*)(bufb + (HALF) * 32768 + aro + 4096 + ps0);                   \
    av[1] = *(const v4i*)(bufb + (HALF) * 32768 + aro + 6144 + ps0);                   \
    av[2] = *(const v4i*)(bufb + (HALF) * 32768 + aro + 4096 + ps1);                   \
    av[3] = *(const v4i*)(bufb + (HALF) * 32768 + aro + 6144 + ps1);                   \
} while (0)

// 8 MFMA: rows (RB,RB+1) x cols (0,1) x k-slices (0,1)
#define MFMA8(RB) do {                                                                 \
    acc[RB][0]     = __builtin_amdgcn_mfma_i32_32x32x32_i8(av[0], bv[0], acc[RB][0], 0, 0, 0);     \
    acc[RB + 1][0] = __builtin_amdgcn_mfma_i32_32x32x32_i8(av[1], bv[0], acc[RB + 1][0], 0, 0, 0); \
    acc[RB][1]     = __builtin_amdgcn_mfma_i32_32x32x32_i8(av[0], bv[1], acc[RB][1], 0, 0, 0);     \
    acc[RB + 1][1] = __builtin_amdgcn_mfma_i32_32x32x32_i8(av[1], bv[1], acc[RB + 1][1], 0, 0, 0); \
    acc[RB][0]     = __builtin_amdgcn_mfma_i32_32x32x32_i8(av[2], bv[2], acc[RB][0], 0, 0, 0);     \
    acc[RB + 1][0] = __builtin_amdgcn_mfma_i32_32x32x32_i8(av[3], bv[2], acc[RB + 1][0], 0, 0, 0); \
    acc[RB][1]     = __builtin_amdgcn_mfma_i32_32x32x32_i8(av[2], bv[3], acc[RB][1], 0, 0, 0);     \
    acc[RB + 1][1] = __builtin_amdgcn_mfma_i32_32x32x32_i8(av[3], bv[3], acc[RB + 1][1], 0, 0, 0); \
} while (0)

// One K-tile = 4 phases, ONE barrier per phase (phase-end). Staging: ph1-2 -> (U+1).H1,
// ph3-4 -> (U+2).H0. Counted vmcnt before the barriers ending ph2/ph4.
#define TILE_BODY(U, DOS12, DOS34, W2STR, W4STR) do {                                  \
    signed char* bufb = smem + ((U) & 1) * 65536;                                      \
    v4i av[4], bv[4];                                                                  \
    /* phase 1: half0, rb0-1 */                                                        \
    PH_READ_AB(0);                                                                     \
    if (DOS12) STG((U) + 1, 1, 0);                                                     \
    LGKM0; PRIO1; MFMA8(0); PRIO0; BAR;                                                \
    /* phase 2: half0, rb2-3 */                                                        \
    PH_READ_A2(0);                                                                     \
    if (DOS12) STG((U) + 1, 1, 128);                                                   \
    LGKM0; PRIO1; MFMA8(2); PRIO0;                                                     \
    asm volatile("s_waitcnt " W2STR ::: "memory"); BAR;                                \
    /* phase 3: half1, rb0-1 */                                                        \
    PH_READ_AB(1);                                                                     \
    if (DOS34) STG((U) + 2, 0, 0);                                                     \
    LGKM0; PRIO1; MFMA8(0); PRIO0; BAR;                                                \
    /* phase 4: half1, rb2-3 */                                                        \
    PH_READ_A2(1);                                                                     \
    if (DOS34) STG((U) + 2, 0, 128);                                                   \
    LGKM0; PRIO1; MFMA8(2); PRIO0;                                                     \
    asm volatile("s_waitcnt " W4STR ::: "memory"); BAR;                                \
} while (0)

    // ---- prologue: 0.H0, 0.H1, 1.H0 (12 loads/wave); drain 0.H0 ----
    STG(0, 0, 0);  STG(0, 0, 128);
    STG(0, 1, 0);  STG(0, 1, 128);
    STG(1, 0, 0);  STG(1, 0, 128);
    asm volatile("s_waitcnt vmcnt(8)" ::: "memory");
    BAR;

    for (int u = 0; u < NT - 2; ++u)
        TILE_BODY(u, true, true, "vmcnt(8)", "vmcnt(8)");
    TILE_BODY(NT - 2, true,  false, "vmcnt(8)", "vmcnt(4)");
    TILE_BODY(NT - 1, false, false, "vmcnt(0)", "vmcnt(0)");

    // ---- epilogue: dequant + bias, fp32 store ----
    // 32x32 C/D map: col = lane&31, row = (reg&3) + 8*(reg>>2) + 4*(lane>>5)
    const int orow0 = bm + wr * 128;
    const int ocol0 = bn + wc * 64;
#pragma unroll
    for (int rb = 0; rb < 4; ++rb) {
#pragma unroll
        for (int cb = 0; cb < 2; ++cb) {
            const int col = ocol0 + cb * 32 + l31;
            const float wb = wsc[col];
            const float bb = bias[col];
#pragma unroll
            for (int r = 0; r < 16; ++r) {
                const int row = orow0 + rb * 32 + (r & 3) + 8 * (r >> 2) + 4 * hi;
                C[(size_t)row * Ndim + col] = (float)acc[rb][cb][r] * sx[row] * wb + bb;
            }
        }
    }
#undef STG
#undef BAR
#undef LGKM0
#undef PRIO1
#undef PRIO0
#undef PH_READ_AB
#undef PH_READ_A2
#undef MFMA8
#undef TILE_BODY
}

extern "C" void kernel_launch(void* const* d_in, const int* in_sizes, int n_in,
                              void* d_out, int out_size, void* d_ws, size_t ws_size,
                              hipStream_t stream) {
    (void)in_sizes; (void)n_in; (void)out_size; (void)ws_size;
    const int*   x_q  = (const int*)d_in[0];
    const float* sx   = (const float*)d_in[1];
    const int*   w_q  = (const int*)d_in[2];
    const float* wsc  = (const float*)d_in[3];
    const float* bias = (const float*)d_in[4];
    float* out = (float*)d_out;

    signed char* x8 = (signed char*)d_ws;
    signed char* w8 = x8 + (size_t)MtotC * Kdim;

    const size_t nx = (size_t)MtotC * Kdim;   // 32 Mi
    const size_t nw = (size_t)Ndim * Kdim;    // 16 Mi

    pack_i32_to_i8<<<3072, 256, 0, stream>>>(x_q, w_q, x8, w8, nx / 4, nw / 4);

    static bool attr_set = false;
    if (!attr_set) {
        hipFuncSetAttribute((const void*)i8gemm_kernel,
                            hipFuncAttributeMaxDynamicSharedMemorySize, 131072);
        attr_set = true;
    }

    const int nwg = (MtotC / BM) * (Ndim / BN);  // 512
    i8gemm_kernel<<<nwg, 512, 131072, stream>>>(x8, w8, sx, wsc, bias, out);
}

// Round 8
// 190.593 us; speedup vs baseline: 1.0845x; 1.0845x over previous
//
#include <hip/hip_runtime.h>

typedef int v4i __attribute__((ext_vector_type(4)));

constexpr int Kdim = 4096;
constexpr int Ndim = 4096;
constexpr int MtotC = 8192;
constexpr int BM = 256;
constexpr int BN = 256;
constexpr int BKB = 128;          // K-bytes per LDS tile (2 halves of 64B)
constexpr int NT = Kdim / BKB;    // 32 K-tiles

// ---------------- pack int32 -> int8 (both tensors, one launch) ----------------
__global__ void pack_i32_to_i8(const int* __restrict__ xq, const int* __restrict__ wq,
                               signed char* __restrict__ x8, signed char* __restrict__ w8,
                               size_t nx4, size_t nw4) {
    size_t i = (size_t)blockIdx.x * blockDim.x + threadIdx.x;
    size_t stride = (size_t)gridDim.x * blockDim.x;
    size_t tot = nx4 + nw4;
    for (size_t j = i; j < tot; j += stride) {
        if (j < nx4) {
            const int4 v = ((const int4*)xq)[j];
            char4 c;
            c.x = (signed char)v.x; c.y = (signed char)v.y;
            c.z = (signed char)v.z; c.w = (signed char)v.w;
            ((char4*)x8)[j] = c;
        } else {
            const size_t k = j - nx4;
            const int4 v = ((const int4*)wq)[k];
            char4 c;
            c.x = (signed char)v.x; c.y = (signed char)v.y;
            c.z = (signed char)v.z; c.w = (signed char)v.w;
            ((char4*)w8)[k] = c;
        }
    }
}

// ---------------- int8 GEMM, 256x256 tile, 16x16x64 MFMA, compiler-scheduled K-tile ----------------
// LDS: 2 bufs x 2 halves x (A 16KB + B 16KB) = 128KB.
// Half h of K-tile t holds K-bytes [t*128 + h*64, +64) for 256 A-rows + 256 B-rows.
// 16B-slot swizzle within a 64B row: slot' = slot ^ ((row>>1)&3)  (R4-verified: 0 conflicts).
// Per K-tile: {24 ds_read_b128 + 64 MFMA, compiler-interleaved lgkmcnt} ; BAR ;
//             stage tile U+2 (8 gload_lds/thread) ; vmcnt(8) ; BAR.
__global__ __launch_bounds__(512, 2) void i8gemm_kernel(
    const signed char* __restrict__ A,
    const signed char* __restrict__ W,
    const float* __restrict__ sx,
    const float* __restrict__ wsc,
    const float* __restrict__ bias,
    float* __restrict__ C)
{
    extern __shared__ signed char smem[];

    const int tid  = threadIdx.x;
    const int wave = tid >> 6;
    const int lane = tid & 63;
    const int wr = wave >> 2;     // 0..1  (128-row strip)
    const int wc = wave & 3;      // 0..3  (64-col strip)

    // XCD-aware swizzle: 8 regions of 8bm x 8bn
    const int xr_ = blockIdx.x & 7;
    const int idx = blockIdx.x >> 3;
    const int bm = ((xr_ & 3) * 8 + (idx & 7)) * BM;
    const int bn = ((xr_ >> 2) * 8 + (idx >> 3)) * BN;

    // ---- staging constants (per thread: 1 A + 1 B gload_lds per STG call) ----
    const int srow_in = wave * 16 + (lane >> 2);            // 0..127
    const int sslotp  = lane & 3;                           // LDS slot'
    const int gslot   = sslotp ^ ((srow_in >> 1) & 3);      // pre-inverse-swizzled global slot
    const signed char* Ag = A + (size_t)(bm + srow_in) * Kdim + gslot * 16;
    const signed char* Wg = W + (size_t)(bn + srow_in) * Kdim + gslot * 16;
    const int sdst = srow_in * 64 + sslotp * 16;            // within-half LDS offset

    // ---- fragment read constants (16x16x64: row/col = lane&15, 16B k-slot = lane>>4) ----
    const int frow = lane & 15;
    const int fsl  = lane >> 4;
    const int rsw  = ((fsl ^ ((frow >> 1) & 3)) << 4);      // swizzled 16B slot byte
    const int aro  = (wr * 128 + frow) * 64 + rsw;          // + f*1024 + half*32768
    const int bro  = 16384 + (wc * 64 + frow) * 64 + rsw;   // + g*1024 + half*32768

    v4i acc[8][4];
#pragma unroll
    for (int f = 0; f < 8; ++f)
#pragma unroll
        for (int g = 0; g < 4; ++g)
#pragma unroll
            for (int e = 0; e < 4; ++e) acc[f][g][e] = 0;

#define STG(KT, HALF, RB) do {                                                         \
    __builtin_amdgcn_global_load_lds(                                                  \
        (const __attribute__((address_space(1))) void*)(Ag + (size_t)(RB) * Kdim + (KT) * BKB + (HALF) * 64), \
        (__attribute__((address_space(3))) void*)(smem + ((KT) & 1) * 65536 + (HALF) * 32768 + (RB) * 64 + sdst), \
        16, 0, 0);                                                                     \
    __builtin_amdgcn_global_load_lds(                                                  \
        (const __attribute__((address_space(1))) void*)(Wg + (size_t)(RB) * Kdim + (KT) * BKB + (HALF) * 64), \
        (__attribute__((address_space(3))) void*)(smem + ((KT) & 1) * 65536 + (HALF) * 32768 + 16384 + (RB) * 64 + sdst), \
        16, 0, 0);                                                                     \
} while (0)

#define STAGEFULL(KT) do {                                                             \
    STG(KT, 0, 0);  STG(KT, 0, 128);                                                   \
    STG(KT, 1, 0);  STG(KT, 1, 128);                                                   \
} while (0)

#define BAR __builtin_amdgcn_s_barrier()

    // ---- prologue: stage tiles 0 and 1 fully (16 loads/thread); drain tile 0 ----
    STAGEFULL(0);
    STAGEFULL(1);
    asm volatile("s_waitcnt vmcnt(8)" ::: "memory");
    BAR;

    for (int u = 0; u < NT; ++u) {
        const signed char* bufb = smem + (u & 1) * 65536;

        // ---- compute tile u: 24 ds_read_b128 + 64 MFMA, compiler-scheduled ----
        v4i av0[8], bv0[4], av1[8], bv1[4];
#pragma unroll
        for (int g = 0; g < 4; ++g) bv0[g] = *(const v4i*)(bufb + bro + g * 1024);
#pragma unroll
        for (int f = 0; f < 8; ++f) av0[f] = *(const v4i*)(bufb + aro + f * 1024);
#pragma unroll
        for (int g = 0; g < 4; ++g) bv1[g] = *(const v4i*)(bufb + 32768 + bro + g * 1024);
#pragma unroll
        for (int f = 0; f < 8; ++f) av1[f] = *(const v4i*)(bufb + 32768 + aro + f * 1024);

#pragma unroll
        for (int f = 0; f < 8; ++f)
#pragma unroll
            for (int g = 0; g < 4; ++g)
                acc[f][g] = __builtin_amdgcn_mfma_i32_16x16x64_i8(av0[f], bv0[g], acc[f][g], 0, 0, 0);
#pragma unroll
        for (int f = 0; f < 8; ++f)
#pragma unroll
            for (int g = 0; g < 4; ++g)
                acc[f][g] = __builtin_amdgcn_mfma_i32_16x16x64_i8(av1[f], bv1[g], acc[f][g], 0, 0, 0);

        BAR;   // all waves done reading buf[u&1]

        if (u + 2 < NT) {
            STAGEFULL(u + 2);                                   // -> buf[u&1]
            asm volatile("s_waitcnt vmcnt(8)" ::: "memory");    // drain tile u+1
            BAR;
        } else if (u + 1 < NT) {
            asm volatile("s_waitcnt vmcnt(0)" ::: "memory");    // drain last tile
            BAR;
        }
    }

    // ---- epilogue: dequant + bias, fp32 store ----
    // 16x16 C/D map: col = lane&15, row = (lane>>4)*4 + reg
    const int orow0 = bm + wr * 128;
    const int ocol0 = bn + wc * 64;
    float wsv[4], bvv[4];
#pragma unroll
    for (int g = 0; g < 4; ++g) {
        const int col = ocol0 + g * 16 + frow;
        wsv[g] = wsc[col];
        bvv[g] = bias[col];
    }
#pragma unroll
    for (int f = 0; f < 8; ++f) {
#pragma unroll
        for (int jr = 0; jr < 4; ++jr) {
            const int row = orow0 + f * 16 + fsl * 4 + jr;
            const float s = sx[row];
#pragma unroll
            for (int g = 0; g < 4; ++g) {
                const int col = ocol0 + g * 16 + frow;
                C[(size_t)row * Ndim + col] = (float)acc[f][g][jr] * s * wsv[g] + bvv[g];
            }
        }
    }
#undef STG
#undef STAGEFULL
#undef BAR
}

extern "C" void kernel_launch(void* const* d_in, const int* in_sizes, int n_in,
                              void* d_out, int out_size, void* d_ws, size_t ws_size,
                              hipStream_t stream) {
    (void)in_sizes; (void)n_in; (void)out_size; (void)ws_size;
    const int*   x_q  = (const int*)d_in[0];
    const float* sx   = (const float*)d_in[1];
    const int*   w_q  = (const int*)d_in[2];
    const float* wsc  = (const float*)d_in[3];
    const float* bias = (const float*)d_in[4];
    float* out = (float*)d_out;

    signed char* x8 = (signed char*)d_ws;
    signed char* w8 = x8 + (size_t)MtotC * Kdim;

    const size_t nx = (size_t)MtotC * Kdim;   // 32 Mi
    const size_t nw = (size_t)Ndim * Kdim;    // 16 Mi

    pack_i32_to_i8<<<3072, 256, 0, stream>>>(x_q, w_q, x8, w8, nx / 4, nw / 4);

    static bool attr_set = false;
    if (!attr_set) {
        hipFuncSetAttribute((const void*)i8gemm_kernel,
                            hipFuncAttributeMaxDynamicSharedMemorySize, 131072);
        attr_set = true;
    }

    const int nwg = (MtotC / BM) * (Ndim / BN);  // 512
    i8gemm_kernel<<<nwg, 512, 131072, stream>>>(x8, w8, sx, wsc, bias, out);
}